// Round 7
// baseline (11254.646 us; speedup 1.0000x reference)
//
#include <hip/hip_runtime.h>
#include <hip/hip_cooperative_groups.h>

namespace cg = cooperative_groups;

#define B_ 64
#define S_ 128
#define H_ 512

// ws layout (f32): gi [128][64][1536] = 12,582,912 ; hhist [129][64][512] = 4,227,072
#define GI_ELEMS 12582912ull

// ---------------------------------------------------------------------------
// gi[t][b][g*512+i] = emb[dec[b][t]] . W_ih[g*512+i][:] + b_ih  (all t parallel)
// grid (128 t, 64 ig) x 512 thr; block stages x[64][512] in LDS (pad 516),
// thread (b = tid&63, v = tid>>6) computes 3 gate dots (full k) for i = ig*8+v.
// W_ih rows are wave-uniform -> broadcast loads from L2.
// ---------------------------------------------------------------------------
__global__ __launch_bounds__(512, 1) void gi_gemm(
    const int* __restrict__ dec, const float* __restrict__ emb,
    const float* __restrict__ wih, const float* __restrict__ bih,
    float* __restrict__ gi)
{
  __shared__ __align__(16) float xs[64 * 516];   // 132,096 B
  const int tid = threadIdx.x;
  const int t  = blockIdx.x;
  const int ig = blockIdx.y;

  {
    const int r = tid >> 3, c0 = (tid & 7) * 64;
    const int tok = dec[r * S_ + t];
    const float* src = emb + (size_t)tok * H_ + c0;
    float* dst = xs + r * 516 + c0;
    #pragma unroll
    for (int m = 0; m < 16; ++m) ((float4*)dst)[m] = ((const float4*)src)[m];
  }
  __syncthreads();

  const int b = tid & 63, v = tid >> 6;
  const int i = ig * 8 + v;
  const float* xp = xs + b * 516;
  const float* w0 = wih + (size_t)(i) * H_;
  const float* w1 = wih + (size_t)(512 + i) * H_;
  const float* w2 = wih + (size_t)(1024 + i) * H_;
  float a0 = 0.f, a1 = 0.f, a2 = 0.f;
  #pragma unroll 4
  for (int k4 = 0; k4 < 128; ++k4) {
    const float4 x4 = ((const float4*)xp)[k4];
    const float4 q0 = ((const float4*)w0)[k4];
    const float4 q1 = ((const float4*)w1)[k4];
    const float4 q2 = ((const float4*)w2)[k4];
    a0 = fmaf(x4.x, q0.x, a0); a0 = fmaf(x4.y, q0.y, a0);
    a0 = fmaf(x4.z, q0.z, a0); a0 = fmaf(x4.w, q0.w, a0);
    a1 = fmaf(x4.x, q1.x, a1); a1 = fmaf(x4.y, q1.y, a1);
    a1 = fmaf(x4.z, q1.z, a1); a1 = fmaf(x4.w, q1.w, a1);
    a2 = fmaf(x4.x, q2.x, a2); a2 = fmaf(x4.y, q2.y, a2);
    a2 = fmaf(x4.z, q2.z, a2); a2 = fmaf(x4.w, q2.w, a2);
  }
  const size_t base = ((size_t)t * B_ + b) * 1536;
  gi[base + i]        = a0 + bih[i];
  gi[base + 512 + i]  = a1 + bih[512 + i];
  gi[base + 1024 + i] = a2 + bih[1024 + i];
}

// ---------------------------------------------------------------------------
// Persistent GRU recurrence. 256 cooperative blocks (1/CU), 512 threads.
// Block p owns h-indices i0=2p, i0+1 (6 W_hh rows in LDS, loaded once).
// Per step: stage h(t) [64][512] in LDS -> 6 dots (k split 8 ways) ->
// LDS partial reduce -> gates -> write h(t+1) to hhist -> grid.sync.
// ---------------------------------------------------------------------------
__global__ __launch_bounds__(512, 1) void gru_persist(
    const float* __restrict__ gi, const float* __restrict__ eh,
    const float* __restrict__ whh, const float* __restrict__ bhh,
    float* __restrict__ hhist)
{
  __shared__ __align__(16) float wl[6 * 512];     // 12,288 B
  __shared__ __align__(16) float hl[64 * 516];    // 132,096 B
  __shared__ __align__(16) float part[6 * 64 * 8];// 12,288 B  -> 156,672 total
  cg::grid_group grid = cg::this_grid();
  const int tid = threadIdx.x;
  const int i0 = blockIdx.x * 2;

  // weights once: row r=(g*2+il) <- whh[g*512 + i0+il][:]
  #pragma unroll
  for (int r = 0; r < 6; ++r) {
    const int g = r >> 1, il = r & 1;
    wl[r * 512 + tid] = whh[((size_t)(g * 512 + i0 + il)) * H_ + tid];
  }
  // epilogue-thread constants
  float bh_r = 0.f, bh_z = 0.f, bh_n = 0.f;
  int eb = 0, eil = 0;
  if (tid < 128) {
    eb = tid & 63; eil = tid >> 6;
    bh_r = bhh[i0 + eil];
    bh_z = bhh[512 + i0 + eil];
    bh_n = bhh[1024 + i0 + eil];
  }

  const int sb = tid >> 3;            // stage row
  const int sc = (tid & 7) * 64;      // stage col
  const int db = tid & 63;            // dot batch
  const int du = tid >> 6;            // dot k-octant (wave-uniform)

  for (int t = 0; t < S_; ++t) {
    if (t > 0) { __threadfence(); grid.sync(); }
    // stage h(t)
    {
      const float* hsrc = (t == 0) ? (eh + sb * H_ + sc)
                                   : (hhist + (size_t)t * (B_ * H_) + sb * H_ + sc);
      float* hdst = hl + sb * 516 + sc;
      #pragma unroll
      for (int m = 0; m < 16; ++m) ((float4*)hdst)[m] = ((const float4*)hsrc)[m];
    }
    // prefetch gi (hidden under the dots)
    float gxr = 0.f, gxz = 0.f, gxn = 0.f;
    if (tid < 128) {
      const float* gp = gi + ((size_t)t * B_ + eb) * 1536 + i0 + eil;
      gxr = gp[0]; gxz = gp[512]; gxn = gp[1024];
    }
    __syncthreads();

    float acc[6] = {0.f, 0.f, 0.f, 0.f, 0.f, 0.f};
    const float* hp = hl + db * 516 + du * 64;
    const float* wp = wl + du * 64;
    #pragma unroll 4
    for (int k4 = 0; k4 < 16; ++k4) {
      const float4 h4 = ((const float4*)hp)[k4];
      #pragma unroll
      for (int r = 0; r < 6; ++r) {
        const float4 w4 = *(const float4*)(wp + r * 512 + k4 * 4);
        acc[r] = fmaf(h4.x, w4.x, acc[r]);
        acc[r] = fmaf(h4.y, w4.y, acc[r]);
        acc[r] = fmaf(h4.z, w4.z, acc[r]);
        acc[r] = fmaf(h4.w, w4.w, acc[r]);
      }
    }
    #pragma unroll
    for (int r = 0; r < 6; ++r) part[(r * 64 + db) * 8 + du] = acc[r];
    __syncthreads();

    if (tid < 128) {
      float gh[3];
      #pragma unroll
      for (int g = 0; g < 3; ++g) {
        const float* pp = part + ((g * 2 + eil) * 64 + eb) * 8;
        const float4 a = ((const float4*)pp)[0];
        const float4 c = ((const float4*)pp)[1];
        gh[g] = ((a.x + a.y) + (a.z + a.w)) + ((c.x + c.y) + (c.z + c.w));
      }
      const float rr = 1.f / (1.f + expf(-(gxr + gh[0] + bh_r)));
      const float zz = 1.f / (1.f + expf(-(gxz + gh[1] + bh_z)));
      const float nn = tanhf(gxn + rr * (gh[2] + bh_n));
      const float hold = hl[eb * 516 + i0 + eil];
      hhist[(size_t)(t + 1) * (B_ * H_) + eb * H_ + i0 + eil] =
          (1.f - zz) * nn + zz * hold;
    }
  }
}

// ---------------------------------------------------------------------------
// Attention for all (b, tt) off hhist. Block (b, tg): 8 tt's share one
// streaming pass over enc[b] per phase. Writes both halves of out.
// ---------------------------------------------------------------------------
__global__ __launch_bounds__(256) void attn_kernel(
    const float* __restrict__ enc, const float* __restrict__ hhist,
    float* __restrict__ out)
{
  __shared__ __align__(16) float h8[8 * 512];     // 16 KB
  __shared__ __align__(16) float sraw[8 * 128];   // 4 KB
  __shared__ __align__(16) float pT[128 * 8];     // 4 KB
  const int tid = threadIdx.x;
  const int bb = blockIdx.x >> 4;
  const int tg = blockIdx.x & 15;

  {
    const int j = tid >> 5, c0 = (tid & 31) * 16;
    const float* src = hhist + (size_t)(tg * 8 + j + 1) * (B_ * H_) + bb * H_ + c0;
    float* dst = h8 + j * 512 + c0;
    #pragma unroll
    for (int m = 0; m < 4; ++m) ((float4*)dst)[m] = ((const float4*)src)[m];
  }
  __syncthreads();

  // scores: thread (s, kh) accumulates 8 j's over its k-half
  {
    const int s = tid >> 1, kh = tid & 1;
    const float* erow = enc + ((size_t)bb * S_ + s) * H_ + kh * 256;
    float acc[8] = {0.f, 0.f, 0.f, 0.f, 0.f, 0.f, 0.f, 0.f};
    #pragma unroll 2
    for (int k4 = 0; k4 < 64; ++k4) {
      const float4 e4 = ((const float4*)erow)[k4];
      #pragma unroll
      for (int j = 0; j < 8; ++j) {
        const float4 h4 = *(const float4*)(h8 + j * 512 + kh * 256 + k4 * 4);
        acc[j] = fmaf(e4.x, h4.x, acc[j]);
        acc[j] = fmaf(e4.y, h4.y, acc[j]);
        acc[j] = fmaf(e4.z, h4.z, acc[j]);
        acc[j] = fmaf(e4.w, h4.w, acc[j]);
      }
    }
    #pragma unroll
    for (int j = 0; j < 8; ++j) {
      const float o = __shfl_xor(acc[j], 1);
      if (kh == 0) sraw[j * 128 + s] = acc[j] + o;
    }
  }
  __syncthreads();

  // softmax: 8 j-groups of 32 lanes, 4 s each (all shuffles stay in-group)
  {
    const int j = tid >> 5, ln = tid & 31;
    const float v0 = sraw[j * 128 + ln];
    const float v1 = sraw[j * 128 + 32 + ln];
    const float v2 = sraw[j * 128 + 64 + ln];
    const float v3 = sraw[j * 128 + 96 + ln];
    float mx = fmaxf(fmaxf(v0, v1), fmaxf(v2, v3));
    #pragma unroll
    for (int o = 16; o > 0; o >>= 1) mx = fmaxf(mx, __shfl_xor(mx, o));
    const float e0 = expf(v0 - mx), e1 = expf(v1 - mx);
    const float e2 = expf(v2 - mx), e3 = expf(v3 - mx);
    float sm = (e0 + e1) + (e2 + e3);
    #pragma unroll
    for (int o = 16; o > 0; o >>= 1) sm += __shfl_xor(sm, o);
    const float inv = 1.f / sm;
    pT[ln * 8 + j]        = e0 * inv;
    pT[(ln + 32) * 8 + j] = e1 * inv;
    pT[(ln + 64) * 8 + j] = e2 * inv;
    pT[(ln + 96) * 8 + j] = e3 * inv;
  }
  __syncthreads();

  // context + output: thread owns 2 i's for all 8 j
  {
    const int i2 = tid * 2;
    float c0[8] = {0,0,0,0,0,0,0,0}, c1[8] = {0,0,0,0,0,0,0,0};
    const float* ecol = enc + (size_t)bb * (S_ * H_) + i2;
    for (int s = 0; s < 128; ++s) {
      const float2 ev = *(const float2*)(ecol + (size_t)s * H_);
      const float4 p0 = ((const float4*)(pT + s * 8))[0];
      const float4 p1 = ((const float4*)(pT + s * 8))[1];
      c0[0] = fmaf(p0.x, ev.x, c0[0]); c1[0] = fmaf(p0.x, ev.y, c1[0]);
      c0[1] = fmaf(p0.y, ev.x, c0[1]); c1[1] = fmaf(p0.y, ev.y, c1[1]);
      c0[2] = fmaf(p0.z, ev.x, c0[2]); c1[2] = fmaf(p0.z, ev.y, c1[2]);
      c0[3] = fmaf(p0.w, ev.x, c0[3]); c1[3] = fmaf(p0.w, ev.y, c1[3]);
      c0[4] = fmaf(p1.x, ev.x, c0[4]); c1[4] = fmaf(p1.x, ev.y, c1[4]);
      c0[5] = fmaf(p1.y, ev.x, c0[5]); c1[5] = fmaf(p1.y, ev.y, c1[5]);
      c0[6] = fmaf(p1.z, ev.x, c0[6]); c1[6] = fmaf(p1.z, ev.y, c1[6]);
      c0[7] = fmaf(p1.w, ev.x, c0[7]); c1[7] = fmaf(p1.w, ev.y, c1[7]);
    }
    #pragma unroll
    for (int j = 0; j < 8; ++j) {
      const int tt = tg * 8 + j;
      const size_t base = ((size_t)bb * S_ + tt) * (2 * H_);
      *(float2*)(out + base + i2)       = *(const float2*)(h8 + j * 512 + i2);
      *(float2*)(out + base + 512 + i2) = make_float2(c0[j], c1[j]);
    }
  }
}

// ---------------------------------------------------------------------------
extern "C" void kernel_launch(void* const* d_in, const int* in_sizes, int n_in,
                              void* d_out, int out_size, void* d_ws, size_t ws_size,
                              hipStream_t stream) {
  (void)in_sizes; (void)n_in; (void)out_size; (void)ws_size;
  const int*   dec = (const int*)d_in[0];
  const float* eh  = (const float*)d_in[1];
  const float* enc = (const float*)d_in[2];
  const float* emb = (const float*)d_in[3];
  const float* wih = (const float*)d_in[4];
  const float* whh = (const float*)d_in[5];
  const float* bih = (const float*)d_in[6];
  const float* bhh = (const float*)d_in[7];
  float* out = (float*)d_out;

  float* gi    = (float*)d_ws;                 // 50.3 MB
  float* hhist = (float*)d_ws + GI_ELEMS;      // 16.9 MB (hhist[0] unused)

  gi_gemm<<<dim3(S_, 64), 512, 0, stream>>>(dec, emb, wih, bih, gi);

  void* args[] = {(void*)&gi, (void*)&eh, (void*)&whh, (void*)&bhh, (void*)&hhist};
  hipLaunchCooperativeKernel((const void*)gru_persist, dim3(256), dim3(512),
                             args, 0, stream);

  attn_kernel<<<dim3(B_ * 16), 256, 0, stream>>>(enc, hhist, out);
}